// Round 6
// baseline (500.579 us; speedup 1.0000x reference)
//
#include <hip/hip_runtime.h>

#define N 8192
#define F_IN 256
#define F_OUT 64
#define ALPHA 0.2f
#define LOG2E 1.4426950408889634f

typedef __attribute__((ext_vector_type(8))) short bf16x8;
typedef __attribute__((ext_vector_type(4))) float f32x4;
typedef __attribute__((ext_vector_type(4))) unsigned u32x4;
typedef __attribute__((ext_vector_type(4))) unsigned short u16x4;

// f32 -> bf16 round-to-nearest-even (finite values only)
__device__ __forceinline__ unsigned short f2bf(float x) {
    unsigned u = __float_as_uint(x);
    u = (u + 0x7FFFu + ((u >> 16) & 1u)) >> 16;
    return (unsigned short)u;
}
__device__ __forceinline__ float bf2f(unsigned short h) {
    return __uint_as_float((unsigned)h << 16);
}
__device__ __forceinline__ float fast_exp2(float x) {
#if __has_builtin(__builtin_amdgcn_exp2f)
    return __builtin_amdgcn_exp2f(x);
#else
    return __expf(x * 0.6931471805599453f);
#endif
}

// ---------------------------------------------------------------------------
// prep: Wa1 = W@a1, Wa2 = W@a2 (fp32); WbT hi/lo bf16 split, [f][k]. 1 block.
// ---------------------------------------------------------------------------
__global__ __launch_bounds__(256) void prep_kernel(
    const float* __restrict__ W, const float* __restrict__ a,
    float* __restrict__ Wa1, float* __restrict__ Wa2,
    unsigned short* __restrict__ WbTh, unsigned short* __restrict__ WbTl) {
    __shared__ float Wl[F_IN][F_OUT + 1];
    __shared__ float al[2 * F_OUT];
    const int t = threadIdx.x;
    for (int it = 0; it < 16; ++it) {
        const int idx = it * 1024 + t * 4;
        const f32x4 v = *(const f32x4*)&W[idx];
        const int r = idx >> 6, c = idx & 63;
        Wl[r][c] = v[0]; Wl[r][c + 1] = v[1]; Wl[r][c + 2] = v[2]; Wl[r][c + 3] = v[3];
    }
    if (t < 128) al[t] = a[t];
    __syncthreads();
    float x1 = 0.f, x2 = 0.f;
#pragma unroll 8
    for (int f = 0; f < F_OUT; ++f) {
        const float wv = Wl[t][f];
        x1 += wv * al[f];
        x2 += wv * al[F_OUT + f];
    }
    Wa1[t] = x1; Wa2[t] = x2;
    const int f = t >> 2, k0 = (t & 3) * 64;
    for (int kk = 0; kk < 64; kk += 8) {
        u32x4 ph, pl;
#pragma unroll
        for (int u = 0; u < 4; ++u) {
            const float w0 = Wl[k0 + kk + 2 * u][f];
            const float w1 = Wl[k0 + kk + 2 * u + 1][f];
            const unsigned short h0 = f2bf(w0), h1 = f2bf(w1);
            const unsigned short l0 = f2bf(w0 - bf2f(h0)), l1 = f2bf(w1 - bf2f(h1));
            ph[u] = (unsigned)h0 | ((unsigned)h1 << 16);
            pl[u] = (unsigned)l0 | ((unsigned)l1 << 16);
        }
        *(u32x4*)&WbTh[f * F_IN + k0 + kk] = ph;
        *(u32x4*)&WbTl[f * F_IN + k0 + kk] = pl;
    }
}

// ---------------------------------------------------------------------------
// scores (exp2-scaled domain): s1c[i] = (h@Wa1)*log2e, s2c[i] = (h@Wa2)*log2e.
// ---------------------------------------------------------------------------
__global__ __launch_bounds__(256) void score_kernel(
    const float* __restrict__ h, const float* __restrict__ Wa1,
    const float* __restrict__ Wa2, float* __restrict__ s1c, float* __restrict__ s2c) {
    __shared__ float w1l[F_IN], w2l[F_IN];
    const int t = threadIdx.x, wave = t >> 6, lane = t & 63;
    w1l[t] = Wa1[t]; w2l[t] = Wa2[t];
    __syncthreads();
    const int row0 = blockIdx.x * 16 + wave * 4;
    const f32x4 wa1 = *(const f32x4*)&w1l[lane * 4];
    const f32x4 wa2 = *(const f32x4*)&w2l[lane * 4];
#pragma unroll
    for (int r = 0; r < 4; ++r) {
        const f32x4 hv = *(const f32x4*)(h + (size_t)(row0 + r) * F_IN + lane * 4);
        float d1 = hv[0] * wa1[0] + hv[1] * wa1[1] + hv[2] * wa1[2] + hv[3] * wa1[3];
        float d2 = hv[0] * wa2[0] + hv[1] * wa2[1] + hv[2] * wa2[2] + hv[3] * wa2[3];
#pragma unroll
        for (int off = 32; off; off >>= 1) {
            d1 += __shfl_down(d1, off, 64);
            d2 += __shfl_down(d2, off, 64);
        }
        if (lane == 0) { s1c[row0 + r] = d1 * LOG2E; s2c[row0 + r] = d2 * LOG2E; }
    }
}

// ---------------------------------------------------------------------------
// whT: WhT[f][i] = bf16((h@W)[i][f]) via hi/lo-split bf16 MFMA (3 products).
// ---------------------------------------------------------------------------
__global__ __launch_bounds__(64) void whT_kernel(
    const float* __restrict__ h, const unsigned short* __restrict__ WbTh,
    const unsigned short* __restrict__ WbTl, unsigned short* __restrict__ WhT) {
    const int lane = threadIdx.x;
    const int mq = lane & 15, quad = lane >> 4;
    const int i0 = blockIdx.x * 16;
    const float* hp = h + (size_t)(i0 + mq) * F_IN + quad * 8;
    const unsigned short* bph = WbTh + mq * F_IN + quad * 8;
    const unsigned short* bpl = WbTl + mq * F_IN + quad * 8;
    f32x4 acc[4] = {{0.f, 0.f, 0.f, 0.f}, {0.f, 0.f, 0.f, 0.f},
                    {0.f, 0.f, 0.f, 0.f}, {0.f, 0.f, 0.f, 0.f}};
#pragma unroll
    for (int kk = 0; kk < 8; ++kk) {
        const f32x4 h0 = *(const f32x4*)(hp + kk * 32);
        const f32x4 h1 = *(const f32x4*)(hp + kk * 32 + 4);
        bf16x8 ah, al;
#pragma unroll
        for (int u = 0; u < 8; ++u) {
            const float v = (u < 4) ? h0[u] : h1[u - 4];
            const unsigned short hi = f2bf(v);
            ah[u] = (short)hi;
            al[u] = (short)f2bf(v - bf2f(hi));
        }
#pragma unroll
        for (int nt = 0; nt < 4; ++nt) {
            const bf16x8 bh = *(const bf16x8*)(bph + nt * 16 * F_IN + kk * 32);
            const bf16x8 bl = *(const bf16x8*)(bpl + nt * 16 * F_IN + kk * 32);
            acc[nt] = __builtin_amdgcn_mfma_f32_16x16x32_bf16(ah, bh, acc[nt], 0, 0, 0);
            acc[nt] = __builtin_amdgcn_mfma_f32_16x16x32_bf16(al, bh, acc[nt], 0, 0, 0);
            acc[nt] = __builtin_amdgcn_mfma_f32_16x16x32_bf16(ah, bl, acc[nt], 0, 0, 0);
        }
    }
#pragma unroll
    for (int nt = 0; nt < 4; ++nt) {
        u16x4 o;
#pragma unroll
        for (int r = 0; r < 4; ++r) o[r] = f2bf(acc[nt][r]);
        *(u16x4*)&WhT[(size_t)(nt * 16 + mq) * N + i0 + quad * 4] = o;
    }
}

// ---------------------------------------------------------------------------
// compress: PURE streamer. adj (256 MB) -> 1-bit mask (8 MB).
// grid 8192 x 256: block = one adj row; thread t packs ints [t*32, t*32+32)
// into one u32 (8 int4 loads in flight, one coalesced u32 store).
// No launch_bounds cap -> no spills (round-5 regression: (256,8) forced
// 64 VGPRs under ~128 live -> scratch spills -> 1.6 TB/s).
// ---------------------------------------------------------------------------
__global__ void compress_kernel(const int* __restrict__ adj,
                                unsigned* __restrict__ maskbits32) {
    const int t = threadIdx.x;
    const int row = blockIdx.x;
    const int* __restrict__ arow = adj + (size_t)row * N + t * 32;
    int4 a[8];
#pragma unroll
    for (int k = 0; k < 8; ++k) a[k] = *(const int4*)(arow + k * 4);
    unsigned b = 0;
#pragma unroll
    for (int k = 0; k < 8; ++k) {
        b |= (a[k].x > 0 ? 1u : 0u) << (4 * k);
        b |= (a[k].y > 0 ? 2u : 0u) << (4 * k);
        b |= (a[k].z > 0 ? 4u : 0u) << (4 * k);
        b |= (a[k].w > 0 ? 8u : 0u) << (4 * k);
    }
    maskbits32[row * 256 + t] = b;
}

// ---------------------------------------------------------------------------
// rowmax: masked per-row max of s2c from the bitmask (8 MB + L1-hot s2c).
// grid 8192 x 256: block = row, thread t owns the same u32 compress wrote.
// mrowc[i] = lrelu(s1c[i] + max{s2c[j] : adj[i][j]>0})  (scaled domain).
// ---------------------------------------------------------------------------
__global__ __launch_bounds__(256) void rowmax_kernel(
    const unsigned* __restrict__ maskbits32, const float* __restrict__ s2c,
    const float* __restrict__ s1c, float* __restrict__ mrowc) {
    __shared__ float red[4];
    const int t = threadIdx.x, wave = t >> 6, lane = t & 63;
    const int row = blockIdx.x;
    const unsigned b = maskbits32[row * 256 + t];
    const float* sp = s2c + t * 32;
    float mx = -3.0e38f;
#pragma unroll
    for (int k = 0; k < 8; ++k) {
        const f32x4 v = *(const f32x4*)(sp + k * 4);
#pragma unroll
        for (int u = 0; u < 4; ++u)
            mx = fmaxf(mx, ((b >> (4 * k + u)) & 1u) ? v[u] : -3.0e38f);
    }
#pragma unroll
    for (int off = 32; off; off >>= 1) mx = fmaxf(mx, __shfl_down(mx, off, 64));
    if (lane == 0) red[wave] = mx;
    __syncthreads();
    if (t == 0) {
        const float mm = fmaxf(fmaxf(red[0], red[1]), fmaxf(red[2], red[3]));
        const float xm = s1c[row] + mm;     // exact masked row max (scaled)
        mrowc[row] = fmaxf(xm, ALPHA * xm); // lrelu monotone + scale-invariant
    }
}

// ---------------------------------------------------------------------------
// attn: phase-2 only (unchanged from round 5, validated). grid 512 x 512.
// ---------------------------------------------------------------------------
#define AROWS 16
__global__ __launch_bounds__(512, 8) void attn_kernel(
    const unsigned char* __restrict__ maskbits,
    const unsigned short* __restrict__ WhT,
    const float* __restrict__ s1c, const float* __restrict__ s2c,
    const float* __restrict__ mrowc, float* __restrict__ out) {
    __shared__ float s1l[AROWS], ml[AROWS];
    __shared__ __align__(16) float accbuf[8][AROWS][F_OUT];   // 32 KB
    __shared__ float rowsums[8][AROWS];

    const int t = threadIdx.x, wave = t >> 6, lane = t & 63;
    const int i0 = blockIdx.x * AROWS;
    if (t < AROWS) { s1l[t] = s1c[i0 + t]; ml[t] = mrowc[i0 + t]; }
    __syncthreads();

    const int mq = lane & 15, quad = lane >> 4;
    const float s1m = s1l[mq];
    const float mr = ml[mq];
    const int jb0 = wave * 1024;

    const unsigned char* __restrict__ mbp =
        maskbits + (size_t)(i0 + mq) * (N / 8) + (jb0 >> 3) + quad;
    const float* __restrict__ sp = s2c + jb0 + quad * 8;
    const unsigned short* __restrict__ wp = WhT + (size_t)mq * N + jb0 + quad * 8;

    f32x4 acc0 = {0.f, 0.f, 0.f, 0.f}, acc1 = acc0, acc2 = acc0, acc3 = acc0, accS = acc0;
    bf16x8 onesf;
#pragma unroll
    for (int u = 0; u < 8; ++u) onesf[u] = (mq == 0) ? (short)0x3F80 : (short)0;

    for (int c = 0; c < 32; ++c) {
        const unsigned mbyte = mbp[c * 4];
        const f32x4 v0 = *(const f32x4*)(sp + c * 32);
        const f32x4 v1 = *(const f32x4*)(sp + c * 32 + 4);
        const unsigned short* wpc = wp + c * 32;
        const bf16x8 b0 = *(const bf16x8*)(wpc);
        const bf16x8 b1 = *(const bf16x8*)(wpc + 16 * N);
        const bf16x8 b2 = *(const bf16x8*)(wpc + 32 * N);
        const bf16x8 b3 = *(const bf16x8*)(wpc + 48 * N);

        bf16x8 af;
#pragma unroll
        for (int jj = 0; jj < 8; ++jj) {
            const float s2k = (jj < 4) ? v0[jj] : v1[jj - 4];
            const float x = s1m + s2k;                   // scaled score
            const float e = fmaxf(x, ALPHA * x);         // lrelu (scale-invariant)
            const float w = ((mbyte >> jj) & 1u) ? fast_exp2(e - mr) : 0.f;  // <= 1
            af[jj] = (short)(__float_as_uint(w) >> 16);  // truncating bf16 (consistent num/den)
        }
        acc0 = __builtin_amdgcn_mfma_f32_16x16x32_bf16(af, b0, acc0, 0, 0, 0);
        acc1 = __builtin_amdgcn_mfma_f32_16x16x32_bf16(af, b1, acc1, 0, 0, 0);
        acc2 = __builtin_amdgcn_mfma_f32_16x16x32_bf16(af, b2, acc2, 0, 0, 0);
        acc3 = __builtin_amdgcn_mfma_f32_16x16x32_bf16(af, b3, acc3, 0, 0, 0);
        accS = __builtin_amdgcn_mfma_f32_16x16x32_bf16(af, onesf, accS, 0, 0, 0);
    }

#pragma unroll
    for (int r = 0; r < 4; ++r) {
        const int row = quad * 4 + r;
        accbuf[wave][row][0 + mq]  = acc0[r];
        accbuf[wave][row][16 + mq] = acc1[r];
        accbuf[wave][row][32 + mq] = acc2[r];
        accbuf[wave][row][48 + mq] = acc3[r];
        if (mq == 0) rowsums[wave][row] = accS[r];
    }
    __syncthreads();

    {
        const int row = t >> 5, f0 = (t & 31) * 2;
        float o0 = 0.f, o1 = 0.f, rs = 0.f;
#pragma unroll
        for (int w = 0; w < 8; ++w) {
            o0 += accbuf[w][row][f0];
            o1 += accbuf[w][row][f0 + 1];
            rs += rowsums[w][row];
        }
        const float inv = (rs > 0.f) ? 1.f / rs : 0.f;
        float2 st = {o0 * inv, o1 * inv};
        *(float2*)&out[(size_t)(i0 + row) * F_OUT + f0] = st;
    }
}

extern "C" void kernel_launch(void* const* d_in, const int* in_sizes, int n_in,
                              void* d_out, int out_size, void* d_ws, size_t ws_size,
                              hipStream_t stream) {
    const float* h   = (const float*)d_in[0];
    const int*   adj = (const int*)d_in[1];
    const float* W   = (const float*)d_in[2];
    const float* a   = (const float*)d_in[3];
    float* out = (float*)d_out;

    // workspace layout (~9.6 MB)
    char* ws = (char*)d_ws;
    unsigned char* maskbits = (unsigned char*)ws;                        // 8 MB
    unsigned short* WhT = (unsigned short*)(ws + (size_t)N * (N / 8));   // 1 MB
    float* s1c  = (float*)((char*)WhT + (size_t)F_OUT * N * 2);          // 32 KB
    float* s2c  = s1c + N;                                               // 32 KB
    float* mrowc = s2c + N;                                              // 32 KB
    float* Wa1 = mrowc + N;
    float* Wa2 = Wa1 + F_IN;
    unsigned short* WbTh = (unsigned short*)(Wa2 + F_IN);                // 32 KB
    unsigned short* WbTl = WbTh + F_OUT * F_IN;                          // 32 KB

    prep_kernel<<<1, 256, 0, stream>>>(W, a, Wa1, Wa2, WbTh, WbTl);
    score_kernel<<<N / 16, 256, 0, stream>>>(h, Wa1, Wa2, s1c, s2c);
    whT_kernel<<<N / 16, 64, 0, stream>>>(h, WbTh, WbTl, WhT);
    compress_kernel<<<N, 256, 0, stream>>>(adj, (unsigned*)maskbits);
    rowmax_kernel<<<N, 256, 0, stream>>>((const unsigned*)maskbits, s2c, s1c, mrowc);
    attn_kernel<<<N / AROWS, 512, 0, stream>>>(maskbits, WhT, s1c, s2c, mrowc, out);
}

// Round 7
// 498.799 us; speedup vs baseline: 1.0036x; 1.0036x over previous
//
#include <hip/hip_runtime.h>

#define N 8192
#define F_IN 256
#define F_OUT 64
#define ALPHA 0.2f
#define LOG2E 1.4426950408889634f

typedef __attribute__((ext_vector_type(8))) short bf16x8;
typedef __attribute__((ext_vector_type(4))) float f32x4;
typedef __attribute__((ext_vector_type(4))) unsigned u32x4;
typedef __attribute__((ext_vector_type(4))) unsigned short u16x4;

// f32 -> bf16 round-to-nearest-even (finite values only)
__device__ __forceinline__ unsigned short f2bf(float x) {
    unsigned u = __float_as_uint(x);
    u = (u + 0x7FFFu + ((u >> 16) & 1u)) >> 16;
    return (unsigned short)u;
}
__device__ __forceinline__ float bf2f(unsigned short h) {
    return __uint_as_float((unsigned)h << 16);
}
__device__ __forceinline__ float fast_exp2(float x) {
#if __has_builtin(__builtin_amdgcn_exp2f)
    return __builtin_amdgcn_exp2f(x);
#else
    return __expf(x * 0.6931471805599453f);
#endif
}

// ---------------------------------------------------------------------------
// prep: Wa1 = W@a1, Wa2 = W@a2 (fp32); WbT hi/lo bf16 split, [f][k]. 1 block.
// ---------------------------------------------------------------------------
__global__ __launch_bounds__(256) void prep_kernel(
    const float* __restrict__ W, const float* __restrict__ a,
    float* __restrict__ Wa1, float* __restrict__ Wa2,
    unsigned short* __restrict__ WbTh, unsigned short* __restrict__ WbTl) {
    __shared__ float Wl[F_IN][F_OUT + 1];
    __shared__ float al[2 * F_OUT];
    const int t = threadIdx.x;
    for (int it = 0; it < 16; ++it) {
        const int idx = it * 1024 + t * 4;
        const f32x4 v = *(const f32x4*)&W[idx];
        const int r = idx >> 6, c = idx & 63;
        Wl[r][c] = v[0]; Wl[r][c + 1] = v[1]; Wl[r][c + 2] = v[2]; Wl[r][c + 3] = v[3];
    }
    if (t < 128) al[t] = a[t];
    __syncthreads();
    float x1 = 0.f, x2 = 0.f;
#pragma unroll 8
    for (int f = 0; f < F_OUT; ++f) {
        const float wv = Wl[t][f];
        x1 += wv * al[f];
        x2 += wv * al[F_OUT + f];
    }
    Wa1[t] = x1; Wa2[t] = x2;
    const int f = t >> 2, k0 = (t & 3) * 64;
    for (int kk = 0; kk < 64; kk += 8) {
        u32x4 ph, pl;
#pragma unroll
        for (int u = 0; u < 4; ++u) {
            const float w0 = Wl[k0 + kk + 2 * u][f];
            const float w1 = Wl[k0 + kk + 2 * u + 1][f];
            const unsigned short h0 = f2bf(w0), h1 = f2bf(w1);
            const unsigned short l0 = f2bf(w0 - bf2f(h0)), l1 = f2bf(w1 - bf2f(h1));
            ph[u] = (unsigned)h0 | ((unsigned)h1 << 16);
            pl[u] = (unsigned)l0 | ((unsigned)l1 << 16);
        }
        *(u32x4*)&WbTh[f * F_IN + k0 + kk] = ph;
        *(u32x4*)&WbTl[f * F_IN + k0 + kk] = pl;
    }
}

// ---------------------------------------------------------------------------
// scores (exp2-scaled domain): s1c[i] = (h@Wa1)*log2e, s2c[i] = (h@Wa2)*log2e.
// ---------------------------------------------------------------------------
__global__ __launch_bounds__(256) void score_kernel(
    const float* __restrict__ h, const float* __restrict__ Wa1,
    const float* __restrict__ Wa2, float* __restrict__ s1c, float* __restrict__ s2c) {
    __shared__ float w1l[F_IN], w2l[F_IN];
    const int t = threadIdx.x, wave = t >> 6, lane = t & 63;
    w1l[t] = Wa1[t]; w2l[t] = Wa2[t];
    __syncthreads();
    const int row0 = blockIdx.x * 16 + wave * 4;
    const f32x4 wa1 = *(const f32x4*)&w1l[lane * 4];
    const f32x4 wa2 = *(const f32x4*)&w2l[lane * 4];
#pragma unroll
    for (int r = 0; r < 4; ++r) {
        const f32x4 hv = *(const f32x4*)(h + (size_t)(row0 + r) * F_IN + lane * 4);
        float d1 = hv[0] * wa1[0] + hv[1] * wa1[1] + hv[2] * wa1[2] + hv[3] * wa1[3];
        float d2 = hv[0] * wa2[0] + hv[1] * wa2[1] + hv[2] * wa2[2] + hv[3] * wa2[3];
#pragma unroll
        for (int off = 32; off; off >>= 1) {
            d1 += __shfl_down(d1, off, 64);
            d2 += __shfl_down(d2, off, 64);
        }
        if (lane == 0) { s1c[row0 + r] = d1 * LOG2E; s2c[row0 + r] = d2 * LOG2E; }
    }
}

// ---------------------------------------------------------------------------
// whT: WhT[f][i] = bf16((h@W)[i][f]) via hi/lo-split bf16 MFMA (3 products).
// grid 512 x 256: block = one 16-row m-tile; wave = one 16-col n-tile
// (8 waves/CU vs round-6's grid-capped 2/CU).
// ---------------------------------------------------------------------------
__global__ __launch_bounds__(256) void whT_kernel(
    const float* __restrict__ h, const unsigned short* __restrict__ WbTh,
    const unsigned short* __restrict__ WbTl, unsigned short* __restrict__ WhT) {
    const int t = threadIdx.x;
    const int nt = t >> 6, lane = t & 63;        // wave = n-tile
    const int mq = lane & 15, quad = lane >> 4;
    const int i0 = blockIdx.x * 16;
    const float* hp = h + (size_t)(i0 + mq) * F_IN + quad * 8;
    const unsigned short* bph = WbTh + (nt * 16 + mq) * F_IN + quad * 8;
    const unsigned short* bpl = WbTl + (nt * 16 + mq) * F_IN + quad * 8;
    f32x4 acc = {0.f, 0.f, 0.f, 0.f};
#pragma unroll
    for (int kk = 0; kk < 8; ++kk) {
        const f32x4 h0 = *(const f32x4*)(hp + kk * 32);
        const f32x4 h1 = *(const f32x4*)(hp + kk * 32 + 4);
        bf16x8 ah, al;
#pragma unroll
        for (int u = 0; u < 8; ++u) {
            const float v = (u < 4) ? h0[u] : h1[u - 4];
            const unsigned short hi = f2bf(v);
            ah[u] = (short)hi;
            al[u] = (short)f2bf(v - bf2f(hi));
        }
        const bf16x8 bh = *(const bf16x8*)(bph + kk * 32);
        const bf16x8 bl = *(const bf16x8*)(bpl + kk * 32);
        acc = __builtin_amdgcn_mfma_f32_16x16x32_bf16(ah, bh, acc, 0, 0, 0);
        acc = __builtin_amdgcn_mfma_f32_16x16x32_bf16(al, bh, acc, 0, 0, 0);
        acc = __builtin_amdgcn_mfma_f32_16x16x32_bf16(ah, bl, acc, 0, 0, 0);
    }
    u16x4 o;
#pragma unroll
    for (int r = 0; r < 4; ++r) o[r] = f2bf(acc[r]);
    *(u16x4*)&WhT[(size_t)(nt * 16 + mq) * N + i0 + quad * 4] = o;
}

// ---------------------------------------------------------------------------
// compress v3: STRICTLY lane-contiguous. Lane l loads int4 #tid (16 B/lane,
// 1 KB/wave-instr = 16 cache lines, no request amplification). Nibble per
// lane, shfl_xor(1) pairs lanes -> byte, even lanes store (coalesced 32 B).
// Rounds 4-6 plateaued at ~1.7 TB/s with 32-128 B lane strides.
// grid 2048 x 256 = 524288 threads x 32 int4 each.
// ---------------------------------------------------------------------------
#define CTHREADS (2048 * 256)
__global__ __launch_bounds__(256) void compress_kernel(
    const int4* __restrict__ adj4, unsigned char* __restrict__ maskbits) {
    const unsigned tid = blockIdx.x * 256 + threadIdx.x;
    const int odd = threadIdx.x & 1;
#pragma unroll 1
    for (int g = 0; g < 8; ++g) {
        int4 a[4];
#pragma unroll
        for (int u = 0; u < 4; ++u)
            a[u] = adj4[(size_t)tid + (size_t)(g * 4 + u) * CTHREADS];
#pragma unroll
        for (int u = 0; u < 4; ++u) {
            const unsigned nib =
                (a[u].x > 0 ? 1u : 0u) | (a[u].y > 0 ? 2u : 0u) |
                (a[u].z > 0 ? 4u : 0u) | (a[u].w > 0 ? 8u : 0u);
            const unsigned pn = (unsigned)__shfl_xor((int)nib, 1, 64);
            if (!odd) {
                const size_t q = (size_t)tid + (size_t)(g * 4 + u) * CTHREADS;
                maskbits[q >> 1] = (unsigned char)(nib | (pn << 4));
            }
        }
    }
}

// ---------------------------------------------------------------------------
// rowmax: masked per-row max of s2c from the bitmask (8 MB + L1-hot s2c).
// ---------------------------------------------------------------------------
__global__ __launch_bounds__(256) void rowmax_kernel(
    const unsigned* __restrict__ maskbits32, const float* __restrict__ s2c,
    const float* __restrict__ s1c, float* __restrict__ mrowc) {
    __shared__ float red[4];
    const int t = threadIdx.x, wave = t >> 6, lane = t & 63;
    const int row = blockIdx.x;
    const unsigned b = maskbits32[row * 256 + t];
    const float* sp = s2c + t * 32;
    float mx = -3.0e38f;
#pragma unroll
    for (int k = 0; k < 8; ++k) {
        const f32x4 v = *(const f32x4*)(sp + k * 4);
#pragma unroll
        for (int u = 0; u < 4; ++u)
            mx = fmaxf(mx, ((b >> (4 * k + u)) & 1u) ? v[u] : -3.0e38f);
    }
#pragma unroll
    for (int off = 32; off; off >>= 1) mx = fmaxf(mx, __shfl_down(mx, off, 64));
    if (lane == 0) red[wave] = mx;
    __syncthreads();
    if (t == 0) {
        const float mm = fmaxf(fmaxf(red[0], red[1]), fmaxf(red[2], red[3]));
        const float xm = s1c[row] + mm;     // exact masked row max (scaled)
        mrowc[row] = fmaxf(xm, ALPHA * xm); // lrelu monotone + scale-invariant
    }
}

// ---------------------------------------------------------------------------
// attn: phase-2 only (validated). grid 512 x 512.
// ---------------------------------------------------------------------------
#define AROWS 16
__global__ __launch_bounds__(512, 8) void attn_kernel(
    const unsigned char* __restrict__ maskbits,
    const unsigned short* __restrict__ WhT,
    const float* __restrict__ s1c, const float* __restrict__ s2c,
    const float* __restrict__ mrowc, float* __restrict__ out) {
    __shared__ float s1l[AROWS], ml[AROWS];
    __shared__ __align__(16) float accbuf[8][AROWS][F_OUT];   // 32 KB
    __shared__ float rowsums[8][AROWS];

    const int t = threadIdx.x, wave = t >> 6, lane = t & 63;
    const int i0 = blockIdx.x * AROWS;
    if (t < AROWS) { s1l[t] = s1c[i0 + t]; ml[t] = mrowc[i0 + t]; }
    __syncthreads();

    const int mq = lane & 15, quad = lane >> 4;
    const float s1m = s1l[mq];
    const float mr = ml[mq];
    const int jb0 = wave * 1024;

    const unsigned char* __restrict__ mbp =
        maskbits + (size_t)(i0 + mq) * (N / 8) + (jb0 >> 3) + quad;
    const float* __restrict__ sp = s2c + jb0 + quad * 8;
    const unsigned short* __restrict__ wp = WhT + (size_t)mq * N + jb0 + quad * 8;

    f32x4 acc0 = {0.f, 0.f, 0.f, 0.f}, acc1 = acc0, acc2 = acc0, acc3 = acc0, accS = acc0;
    bf16x8 onesf;
#pragma unroll
    for (int u = 0; u < 8; ++u) onesf[u] = (mq == 0) ? (short)0x3F80 : (short)0;

    for (int c = 0; c < 32; ++c) {
        const unsigned mbyte = mbp[c * 4];
        const f32x4 v0 = *(const f32x4*)(sp + c * 32);
        const f32x4 v1 = *(const f32x4*)(sp + c * 32 + 4);
        const unsigned short* wpc = wp + c * 32;
        const bf16x8 b0 = *(const bf16x8*)(wpc);
        const bf16x8 b1 = *(const bf16x8*)(wpc + 16 * N);
        const bf16x8 b2 = *(const bf16x8*)(wpc + 32 * N);
        const bf16x8 b3 = *(const bf16x8*)(wpc + 48 * N);

        bf16x8 af;
#pragma unroll
        for (int jj = 0; jj < 8; ++jj) {
            const float s2k = (jj < 4) ? v0[jj] : v1[jj - 4];
            const float x = s1m + s2k;                   // scaled score
            const float e = fmaxf(x, ALPHA * x);         // lrelu (scale-invariant)
            const float w = ((mbyte >> jj) & 1u) ? fast_exp2(e - mr) : 0.f;  // <= 1
            af[jj] = (short)(__float_as_uint(w) >> 16);  // truncating bf16 (consistent num/den)
        }
        acc0 = __builtin_amdgcn_mfma_f32_16x16x32_bf16(af, b0, acc0, 0, 0, 0);
        acc1 = __builtin_amdgcn_mfma_f32_16x16x32_bf16(af, b1, acc1, 0, 0, 0);
        acc2 = __builtin_amdgcn_mfma_f32_16x16x32_bf16(af, b2, acc2, 0, 0, 0);
        acc3 = __builtin_amdgcn_mfma_f32_16x16x32_bf16(af, b3, acc3, 0, 0, 0);
        accS = __builtin_amdgcn_mfma_f32_16x16x32_bf16(af, onesf, accS, 0, 0, 0);
    }

#pragma unroll
    for (int r = 0; r < 4; ++r) {
        const int row = quad * 4 + r;
        accbuf[wave][row][0 + mq]  = acc0[r];
        accbuf[wave][row][16 + mq] = acc1[r];
        accbuf[wave][row][32 + mq] = acc2[r];
        accbuf[wave][row][48 + mq] = acc3[r];
        if (mq == 0) rowsums[wave][row] = accS[r];
    }
    __syncthreads();

    {
        const int row = t >> 5, f0 = (t & 31) * 2;
        float o0 = 0.f, o1 = 0.f, rs = 0.f;
#pragma unroll
        for (int w = 0; w < 8; ++w) {
            o0 += accbuf[w][row][f0];
            o1 += accbuf[w][row][f0 + 1];
            rs += rowsums[w][row];
        }
        const float inv = (rs > 0.f) ? 1.f / rs : 0.f;
        float2 st = {o0 * inv, o1 * inv};
        *(float2*)&out[(size_t)(i0 + row) * F_OUT + f0] = st;
    }
}

extern "C" void kernel_launch(void* const* d_in, const int* in_sizes, int n_in,
                              void* d_out, int out_size, void* d_ws, size_t ws_size,
                              hipStream_t stream) {
    const float* h   = (const float*)d_in[0];
    const int*   adj = (const int*)d_in[1];
    const float* W   = (const float*)d_in[2];
    const float* a   = (const float*)d_in[3];
    float* out = (float*)d_out;

    // workspace layout (~9.6 MB)
    char* ws = (char*)d_ws;
    unsigned char* maskbits = (unsigned char*)ws;                        // 8 MB
    unsigned short* WhT = (unsigned short*)(ws + (size_t)N * (N / 8));   // 1 MB
    float* s1c  = (float*)((char*)WhT + (size_t)F_OUT * N * 2);          // 32 KB
    float* s2c  = s1c + N;                                               // 32 KB
    float* mrowc = s2c + N;                                              // 32 KB
    float* Wa1 = mrowc + N;
    float* Wa2 = Wa1 + F_IN;
    unsigned short* WbTh = (unsigned short*)(Wa2 + F_IN);                // 32 KB
    unsigned short* WbTl = WbTh + F_OUT * F_IN;                          // 32 KB

    prep_kernel<<<1, 256, 0, stream>>>(W, a, Wa1, Wa2, WbTh, WbTl);
    score_kernel<<<N / 16, 256, 0, stream>>>(h, Wa1, Wa2, s1c, s2c);
    whT_kernel<<<N / 16, 256, 0, stream>>>(h, WbTh, WbTl, WhT);
    compress_kernel<<<2048, 256, 0, stream>>>((const int4*)adj, maskbits);
    rowmax_kernel<<<N, 256, 0, stream>>>((const unsigned*)maskbits, s2c, s1c, mrowc);
    attn_kernel<<<N / AROWS, 512, 0, stream>>>(maskbits, WhT, s1c, s2c, mrowc, out);
}

// Round 9
// 449.240 us; speedup vs baseline: 1.1143x; 1.1103x over previous
//
#include <hip/hip_runtime.h>

#define N 8192
#define F_IN 256
#define F_OUT 64
#define ALPHA 0.2f
#define LOG2E 1.4426950408889634f

typedef __attribute__((ext_vector_type(8))) short bf16x8;
typedef __attribute__((ext_vector_type(4))) float f32x4;
typedef __attribute__((ext_vector_type(4))) int i32x4;
typedef __attribute__((ext_vector_type(4))) unsigned u32x4;
typedef __attribute__((ext_vector_type(4))) unsigned short u16x4;

// f32 -> bf16 round-to-nearest-even (finite values only)
__device__ __forceinline__ unsigned short f2bf(float x) {
    unsigned u = __float_as_uint(x);
    u = (u + 0x7FFFu + ((u >> 16) & 1u)) >> 16;
    return (unsigned short)u;
}
__device__ __forceinline__ float bf2f(unsigned short h) {
    return __uint_as_float((unsigned)h << 16);
}
__device__ __forceinline__ float fast_exp2(float x) {
#if __has_builtin(__builtin_amdgcn_exp2f)
    return __builtin_amdgcn_exp2f(x);
#else
    return __expf(x * 0.6931471805599453f);
#endif
}

// ---------------------------------------------------------------------------
// prep: Wa1 = W@a1, Wa2 = W@a2 (fp32); WbT hi/lo bf16 split, [f][k]. 1 block.
// ---------------------------------------------------------------------------
__global__ __launch_bounds__(256) void prep_kernel(
    const float* __restrict__ W, const float* __restrict__ a,
    float* __restrict__ Wa1, float* __restrict__ Wa2,
    unsigned short* __restrict__ WbTh, unsigned short* __restrict__ WbTl) {
    __shared__ float Wl[F_IN][F_OUT + 1];
    __shared__ float al[2 * F_OUT];
    const int t = threadIdx.x;
    for (int it = 0; it < 16; ++it) {
        const int idx = it * 1024 + t * 4;
        const f32x4 v = *(const f32x4*)&W[idx];
        const int r = idx >> 6, c = idx & 63;
        Wl[r][c] = v[0]; Wl[r][c + 1] = v[1]; Wl[r][c + 2] = v[2]; Wl[r][c + 3] = v[3];
    }
    if (t < 128) al[t] = a[t];
    __syncthreads();
    float x1 = 0.f, x2 = 0.f;
#pragma unroll 8
    for (int f = 0; f < F_OUT; ++f) {
        const float wv = Wl[t][f];
        x1 += wv * al[f];
        x2 += wv * al[F_OUT + f];
    }
    Wa1[t] = x1; Wa2[t] = x2;
    const int f = t >> 2, k0 = (t & 3) * 64;
    for (int kk = 0; kk < 64; kk += 8) {
        u32x4 ph, pl;
#pragma unroll
        for (int u = 0; u < 4; ++u) {
            const float w0 = Wl[k0 + kk + 2 * u][f];
            const float w1 = Wl[k0 + kk + 2 * u + 1][f];
            const unsigned short h0 = f2bf(w0), h1 = f2bf(w1);
            const unsigned short l0 = f2bf(w0 - bf2f(h0)), l1 = f2bf(w1 - bf2f(h1));
            ph[u] = (unsigned)h0 | ((unsigned)h1 << 16);
            pl[u] = (unsigned)l0 | ((unsigned)l1 << 16);
        }
        *(u32x4*)&WbTh[f * F_IN + k0 + kk] = ph;
        *(u32x4*)&WbTl[f * F_IN + k0 + kk] = pl;
    }
}

// ---------------------------------------------------------------------------
// scores (exp2-scaled domain): s1c[i] = (h@Wa1)*log2e, s2c[i] = (h@Wa2)*log2e.
// ---------------------------------------------------------------------------
__global__ __launch_bounds__(256) void score_kernel(
    const float* __restrict__ h, const float* __restrict__ Wa1,
    const float* __restrict__ Wa2, float* __restrict__ s1c, float* __restrict__ s2c) {
    __shared__ float w1l[F_IN], w2l[F_IN];
    const int t = threadIdx.x, wave = t >> 6, lane = t & 63;
    w1l[t] = Wa1[t]; w2l[t] = Wa2[t];
    __syncthreads();
    const int row0 = blockIdx.x * 16 + wave * 4;
    const f32x4 wa1 = *(const f32x4*)&w1l[lane * 4];
    const f32x4 wa2 = *(const f32x4*)&w2l[lane * 4];
#pragma unroll
    for (int r = 0; r < 4; ++r) {
        const f32x4 hv = *(const f32x4*)(h + (size_t)(row0 + r) * F_IN + lane * 4);
        float d1 = hv[0] * wa1[0] + hv[1] * wa1[1] + hv[2] * wa1[2] + hv[3] * wa1[3];
        float d2 = hv[0] * wa2[0] + hv[1] * wa2[1] + hv[2] * wa2[2] + hv[3] * wa2[3];
#pragma unroll
        for (int off = 32; off; off >>= 1) {
            d1 += __shfl_down(d1, off, 64);
            d2 += __shfl_down(d2, off, 64);
        }
        if (lane == 0) { s1c[row0 + r] = d1 * LOG2E; s2c[row0 + r] = d2 * LOG2E; }
    }
}

// ---------------------------------------------------------------------------
// whT: WhT[f][i] = bf16((h@W)[i][f]) via hi/lo-split bf16 MFMA (3 products).
// grid 512 x 256: block = 16-row m-tile; wave = 16-col n-tile.
// ---------------------------------------------------------------------------
__global__ __launch_bounds__(256) void whT_kernel(
    const float* __restrict__ h, const unsigned short* __restrict__ WbTh,
    const unsigned short* __restrict__ WbTl, unsigned short* __restrict__ WhT) {
    const int t = threadIdx.x;
    const int nt = t >> 6, lane = t & 63;        // wave = n-tile
    const int mq = lane & 15, quad = lane >> 4;
    const int i0 = blockIdx.x * 16;
    const float* hp = h + (size_t)(i0 + mq) * F_IN + quad * 8;
    const unsigned short* bph = WbTh + (nt * 16 + mq) * F_IN + quad * 8;
    const unsigned short* bpl = WbTl + (nt * 16 + mq) * F_IN + quad * 8;
    f32x4 acc = {0.f, 0.f, 0.f, 0.f};
#pragma unroll
    for (int kk = 0; kk < 8; ++kk) {
        const f32x4 h0 = *(const f32x4*)(hp + kk * 32);
        const f32x4 h1 = *(const f32x4*)(hp + kk * 32 + 4);
        bf16x8 ah, al;
#pragma unroll
        for (int u = 0; u < 8; ++u) {
            const float v = (u < 4) ? h0[u] : h1[u - 4];
            const unsigned short hi = f2bf(v);
            ah[u] = (short)hi;
            al[u] = (short)f2bf(v - bf2f(hi));
        }
        const bf16x8 bh = *(const bf16x8*)(bph + kk * 32);
        const bf16x8 bl = *(const bf16x8*)(bpl + kk * 32);
        acc = __builtin_amdgcn_mfma_f32_16x16x32_bf16(ah, bh, acc, 0, 0, 0);
        acc = __builtin_amdgcn_mfma_f32_16x16x32_bf16(al, bh, acc, 0, 0, 0);
        acc = __builtin_amdgcn_mfma_f32_16x16x32_bf16(ah, bl, acc, 0, 0, 0);
    }
    u16x4 o;
#pragma unroll
    for (int r = 0; r < 4; ++r) o[r] = f2bf(acc[r]);
    *(u16x4*)&WhT[(size_t)(nt * 16 + mq) * N + i0 + quad * 4] = o;
}

// ---------------------------------------------------------------------------
// compress v4b (fused rowmax): block = one adj row (256 thr); thread t handles
// int4 indices {t, t+256, ..., t+1792} -> 8 lane-contiguous 16 B/lane
// NONTEMPORAL loads (FULL row coverage: 2048 int4 = 8192 ints; round 8's NaN
// was seg<2 covering only 1/4 of the row, leaving poisoned mask bytes).
// nt bypasses cache allocation -> avoids evicting the 1 GB of dirty 0xAA
// poison lines the harness fill leaves (theory for the r4-r7 ~1.6 TB/s wall).
// Masked per-row max of s2c computed inline (s2c L1-hot).
// ---------------------------------------------------------------------------
__global__ __launch_bounds__(256) void compress_kernel(
    const int* __restrict__ adj, const float* __restrict__ s2c,
    const float* __restrict__ s1c,
    unsigned char* __restrict__ maskbits, float* __restrict__ mrowc) {
    __shared__ float red[4];
    const int t = threadIdx.x, wave = t >> 6, lane = t & 63;
    const int row = blockIdx.x;
    const int odd = t & 1;
    const int* __restrict__ arow = adj + (size_t)row * N;
    float mx = -3.0e38f;

#pragma unroll
    for (int seg = 0; seg < 8; ++seg) {
        const int idx4 = seg * 256 + t;                 // int4 index within row
        const i32x4 a = __builtin_nontemporal_load((const i32x4*)(arow + idx4 * 4));
        const f32x4 s = *(const f32x4*)(s2c + idx4 * 4); // cacheable, L1-hot
        const unsigned nib =
            (a[0] > 0 ? 1u : 0u) | (a[1] > 0 ? 2u : 0u) |
            (a[2] > 0 ? 4u : 0u) | (a[3] > 0 ? 8u : 0u);
        mx = fmaxf(mx, (a[0] > 0) ? s[0] : -3.0e38f);
        mx = fmaxf(mx, (a[1] > 0) ? s[1] : -3.0e38f);
        mx = fmaxf(mx, (a[2] > 0) ? s[2] : -3.0e38f);
        mx = fmaxf(mx, (a[3] > 0) ? s[3] : -3.0e38f);
        const unsigned pn = (unsigned)__shfl_xor((int)nib, 1, 64);
        if (!odd)
            maskbits[(size_t)row * (N / 8) + (idx4 >> 1)] =
                (unsigned char)(nib | (pn << 4));
    }
#pragma unroll
    for (int off = 32; off; off >>= 1) mx = fmaxf(mx, __shfl_down(mx, off, 64));
    if (lane == 0) red[wave] = mx;
    __syncthreads();
    if (t == 0) {
        const float mm = fmaxf(fmaxf(red[0], red[1]), fmaxf(red[2], red[3]));
        const float xm = s1c[row] + mm;     // exact masked row max (scaled)
        mrowc[row] = fmaxf(xm, ALPHA * xm); // lrelu monotone + scale-invariant
    }
}

// ---------------------------------------------------------------------------
// attn: phase-2 only (validated r5-r7). grid 512 x 512.
// ---------------------------------------------------------------------------
#define AROWS 16
__global__ __launch_bounds__(512, 8) void attn_kernel(
    const unsigned char* __restrict__ maskbits,
    const unsigned short* __restrict__ WhT,
    const float* __restrict__ s1c, const float* __restrict__ s2c,
    const float* __restrict__ mrowc, float* __restrict__ out) {
    __shared__ float s1l[AROWS], ml[AROWS];
    __shared__ __align__(16) float accbuf[8][AROWS][F_OUT];   // 32 KB
    __shared__ float rowsums[8][AROWS];

    const int t = threadIdx.x, wave = t >> 6, lane = t & 63;
    const int i0 = blockIdx.x * AROWS;
    if (t < AROWS) { s1l[t] = s1c[i0 + t]; ml[t] = mrowc[i0 + t]; }
    __syncthreads();

    const int mq = lane & 15, quad = lane >> 4;
    const float s1m = s1l[mq];
    const float mr = ml[mq];
    const int jb0 = wave * 1024;

    const unsigned char* __restrict__ mbp =
        maskbits + (size_t)(i0 + mq) * (N / 8) + (jb0 >> 3) + quad;
    const float* __restrict__ sp = s2c + jb0 + quad * 8;
    const unsigned short* __restrict__ wp = WhT + (size_t)mq * N + jb0 + quad * 8;

    f32x4 acc0 = {0.f, 0.f, 0.f, 0.f}, acc1 = acc0, acc2 = acc0, acc3 = acc0, accS = acc0;
    bf16x8 onesf;
#pragma unroll
    for (int u = 0; u < 8; ++u) onesf[u] = (mq == 0) ? (short)0x3F80 : (short)0;

    for (int c = 0; c < 32; ++c) {
        const unsigned mbyte = mbp[c * 4];
        const f32x4 v0 = *(const f32x4*)(sp + c * 32);
        const f32x4 v1 = *(const f32x4*)(sp + c * 32 + 4);
        const unsigned short* wpc = wp + c * 32;
        const bf16x8 b0 = *(const bf16x8*)(wpc);
        const bf16x8 b1 = *(const bf16x8*)(wpc + 16 * N);
        const bf16x8 b2 = *(const bf16x8*)(wpc + 32 * N);
        const bf16x8 b3 = *(const bf16x8*)(wpc + 48 * N);

        bf16x8 af;
#pragma unroll
        for (int jj = 0; jj < 8; ++jj) {
            const float s2k = (jj < 4) ? v0[jj] : v1[jj - 4];
            const float x = s1m + s2k;                   // scaled score
            const float e = fmaxf(x, ALPHA * x);         // lrelu (scale-invariant)
            const float w = ((mbyte >> jj) & 1u) ? fast_exp2(e - mr) : 0.f;  // <= 1
            af[jj] = (short)(__float_as_uint(w) >> 16);  // truncating bf16 (consistent num/den)
        }
        acc0 = __builtin_amdgcn_mfma_f32_16x16x32_bf16(af, b0, acc0, 0, 0, 0);
        acc1 = __builtin_amdgcn_mfma_f32_16x16x32_bf16(af, b1, acc1, 0, 0, 0);
        acc2 = __builtin_amdgcn_mfma_f32_16x16x32_bf16(af, b2, acc2, 0, 0, 0);
        acc3 = __builtin_amdgcn_mfma_f32_16x16x32_bf16(af, b3, acc3, 0, 0, 0);
        accS = __builtin_amdgcn_mfma_f32_16x16x32_bf16(af, onesf, accS, 0, 0, 0);
    }

#pragma unroll
    for (int r = 0; r < 4; ++r) {
        const int row = quad * 4 + r;
        accbuf[wave][row][0 + mq]  = acc0[r];
        accbuf[wave][row][16 + mq] = acc1[r];
        accbuf[wave][row][32 + mq] = acc2[r];
        accbuf[wave][row][48 + mq] = acc3[r];
        if (mq == 0) rowsums[wave][row] = accS[r];
    }
    __syncthreads();

    {
        const int row = t >> 5, f0 = (t & 31) * 2;
        float o0 = 0.f, o1 = 0.f, rs = 0.f;
#pragma unroll
        for (int w = 0; w < 8; ++w) {
            o0 += accbuf[w][row][f0];
            o1 += accbuf[w][row][f0 + 1];
            rs += rowsums[w][row];
        }
        const float inv = (rs > 0.f) ? 1.f / rs : 0.f;
        float2 st = {o0 * inv, o1 * inv};
        *(float2*)&out[(size_t)(i0 + row) * F_OUT + f0] = st;
    }
}

extern "C" void kernel_launch(void* const* d_in, const int* in_sizes, int n_in,
                              void* d_out, int out_size, void* d_ws, size_t ws_size,
                              hipStream_t stream) {
    const float* h   = (const float*)d_in[0];
    const int*   adj = (const int*)d_in[1];
    const float* W   = (const float*)d_in[2];
    const float* a   = (const float*)d_in[3];
    float* out = (float*)d_out;

    // workspace layout (~9.6 MB)
    char* ws = (char*)d_ws;
    unsigned char* maskbits = (unsigned char*)ws;                        // 8 MB
    unsigned short* WhT = (unsigned short*)(ws + (size_t)N * (N / 8));   // 1 MB
    float* s1c  = (float*)((char*)WhT + (size_t)F_OUT * N * 2);          // 32 KB
    float* s2c  = s1c + N;                                               // 32 KB
    float* mrowc = s2c + N;                                              // 32 KB
    float* Wa1 = mrowc + N;
    float* Wa2 = Wa1 + F_IN;
    unsigned short* WbTh = (unsigned short*)(Wa2 + F_IN);                // 32 KB
    unsigned short* WbTl = WbTh + F_OUT * F_IN;                          // 32 KB

    prep_kernel<<<1, 256, 0, stream>>>(W, a, Wa1, Wa2, WbTh, WbTl);
    score_kernel<<<N / 16, 256, 0, stream>>>(h, Wa1, Wa2, s1c, s2c);
    compress_kernel<<<N, 256, 0, stream>>>(adj, s2c, s1c, maskbits, mrowc);
    whT_kernel<<<N / 16, 256, 0, stream>>>(h, WbTh, WbTl, WhT);
    attn_kernel<<<N / AROWS, 512, 0, stream>>>(maskbits, WhT, s1c, s2c, mrowc, out);
}

// Round 10
// 445.022 us; speedup vs baseline: 1.1248x; 1.0095x over previous
//
#include <hip/hip_runtime.h>

#define N 8192
#define F_IN 256
#define F_OUT 64
#define ALPHA 0.2f
#define LOG2E 1.4426950408889634f

typedef __attribute__((ext_vector_type(8))) short bf16x8;
typedef __attribute__((ext_vector_type(4))) float f32x4;
typedef __attribute__((ext_vector_type(4))) int i32x4;
typedef __attribute__((ext_vector_type(4))) unsigned u32x4;
typedef __attribute__((ext_vector_type(4))) unsigned short u16x4;

// f32 -> bf16 round-to-nearest-even (finite values only)
__device__ __forceinline__ unsigned short f2bf(float x) {
    unsigned u = __float_as_uint(x);
    u = (u + 0x7FFFu + ((u >> 16) & 1u)) >> 16;
    return (unsigned short)u;
}
__device__ __forceinline__ float bf2f(unsigned short h) {
    return __uint_as_float((unsigned)h << 16);
}
__device__ __forceinline__ float fast_exp2(float x) {
#if __has_builtin(__builtin_amdgcn_exp2f)
    return __builtin_amdgcn_exp2f(x);
#else
    return __expf(x * 0.6931471805599453f);
#endif
}

// System-scope + non-temporal paired 16B loads: sc0 sc1 -> bypass L1/L2
// allocation (system scope), nt -> no-reuse hint for the memory-side cache.
// Goal: adj's one-shot 256 MB stream must NOT allocate cache lines, because
// the harness's 1 GB 0xAA poison-fill leaves L3 full of dirty lines and every
// allocation forces a dirty writeback (read becomes read+write, the ~2 TB/s
// wall of r4-r9). waitcnt is INSIDE the asm so the compiler cannot hoist a
// consumer between issue and drain. Early-clobber (=&v) so result tuples
// never alias the address operands.
__device__ __forceinline__ void load2_bypass(const int* p0, const int* p1,
                                             i32x4& r0, i32x4& r1) {
    asm volatile(
        "global_load_dwordx4 %0, %2, off sc0 sc1 nt\n\t"
        "global_load_dwordx4 %1, %3, off sc0 sc1 nt\n\t"
        "s_waitcnt vmcnt(0)"
        : "=&v"(r0), "=&v"(r1)
        : "v"(p0), "v"(p1)
        : "memory");
}

// ---------------------------------------------------------------------------
// prep: Wa1 = W@a1, Wa2 = W@a2 (fp32); WbT hi/lo bf16 split, [f][k]. 1 block.
// ---------------------------------------------------------------------------
__global__ __launch_bounds__(256) void prep_kernel(
    const float* __restrict__ W, const float* __restrict__ a,
    float* __restrict__ Wa1, float* __restrict__ Wa2,
    unsigned short* __restrict__ WbTh, unsigned short* __restrict__ WbTl) {
    __shared__ float Wl[F_IN][F_OUT + 1];
    __shared__ float al[2 * F_OUT];
    const int t = threadIdx.x;
    for (int it = 0; it < 16; ++it) {
        const int idx = it * 1024 + t * 4;
        const f32x4 v = *(const f32x4*)&W[idx];
        const int r = idx >> 6, c = idx & 63;
        Wl[r][c] = v[0]; Wl[r][c + 1] = v[1]; Wl[r][c + 2] = v[2]; Wl[r][c + 3] = v[3];
    }
    if (t < 128) al[t] = a[t];
    __syncthreads();
    float x1 = 0.f, x2 = 0.f;
#pragma unroll 8
    for (int f = 0; f < F_OUT; ++f) {
        const float wv = Wl[t][f];
        x1 += wv * al[f];
        x2 += wv * al[F_OUT + f];
    }
    Wa1[t] = x1; Wa2[t] = x2;
    const int f = t >> 2, k0 = (t & 3) * 64;
    for (int kk = 0; kk < 64; kk += 8) {
        u32x4 ph, pl;
#pragma unroll
        for (int u = 0; u < 4; ++u) {
            const float w0 = Wl[k0 + kk + 2 * u][f];
            const float w1 = Wl[k0 + kk + 2 * u + 1][f];
            const unsigned short h0 = f2bf(w0), h1 = f2bf(w1);
            const unsigned short l0 = f2bf(w0 - bf2f(h0)), l1 = f2bf(w1 - bf2f(h1));
            ph[u] = (unsigned)h0 | ((unsigned)h1 << 16);
            pl[u] = (unsigned)l0 | ((unsigned)l1 << 16);
        }
        *(u32x4*)&WbTh[f * F_IN + k0 + kk] = ph;
        *(u32x4*)&WbTl[f * F_IN + k0 + kk] = pl;
    }
}

// ---------------------------------------------------------------------------
// scores (exp2-scaled domain): s1c[i] = (h@Wa1)*log2e, s2c[i] = (h@Wa2)*log2e.
// ---------------------------------------------------------------------------
__global__ __launch_bounds__(256) void score_kernel(
    const float* __restrict__ h, const float* __restrict__ Wa1,
    const float* __restrict__ Wa2, float* __restrict__ s1c, float* __restrict__ s2c) {
    __shared__ float w1l[F_IN], w2l[F_IN];
    const int t = threadIdx.x, wave = t >> 6, lane = t & 63;
    w1l[t] = Wa1[t]; w2l[t] = Wa2[t];
    __syncthreads();
    const int row0 = blockIdx.x * 16 + wave * 4;
    const f32x4 wa1 = *(const f32x4*)&w1l[lane * 4];
    const f32x4 wa2 = *(const f32x4*)&w2l[lane * 4];
#pragma unroll
    for (int r = 0; r < 4; ++r) {
        const f32x4 hv = *(const f32x4*)(h + (size_t)(row0 + r) * F_IN + lane * 4);
        float d1 = hv[0] * wa1[0] + hv[1] * wa1[1] + hv[2] * wa1[2] + hv[3] * wa1[3];
        float d2 = hv[0] * wa2[0] + hv[1] * wa2[1] + hv[2] * wa2[2] + hv[3] * wa2[3];
#pragma unroll
        for (int off = 32; off; off >>= 1) {
            d1 += __shfl_down(d1, off, 64);
            d2 += __shfl_down(d2, off, 64);
        }
        if (lane == 0) { s1c[row0 + r] = d1 * LOG2E; s2c[row0 + r] = d2 * LOG2E; }
    }
}

// ---------------------------------------------------------------------------
// whT: WhT[f][i] = bf16((h@W)[i][f]) via hi/lo-split bf16 MFMA (3 products).
// grid 512 x 256: block = 16-row m-tile; wave = 16-col n-tile.
// ---------------------------------------------------------------------------
__global__ __launch_bounds__(256) void whT_kernel(
    const float* __restrict__ h, const unsigned short* __restrict__ WbTh,
    const unsigned short* __restrict__ WbTl, unsigned short* __restrict__ WhT) {
    const int t = threadIdx.x;
    const int nt = t >> 6, lane = t & 63;        // wave = n-tile
    const int mq = lane & 15, quad = lane >> 4;
    const int i0 = blockIdx.x * 16;
    const float* hp = h + (size_t)(i0 + mq) * F_IN + quad * 8;
    const unsigned short* bph = WbTh + (nt * 16 + mq) * F_IN + quad * 8;
    const unsigned short* bpl = WbTl + (nt * 16 + mq) * F_IN + quad * 8;
    f32x4 acc = {0.f, 0.f, 0.f, 0.f};
#pragma unroll
    for (int kk = 0; kk < 8; ++kk) {
        const f32x4 h0 = *(const f32x4*)(hp + kk * 32);
        const f32x4 h1 = *(const f32x4*)(hp + kk * 32 + 4);
        bf16x8 ah, al;
#pragma unroll
        for (int u = 0; u < 8; ++u) {
            const float v = (u < 4) ? h0[u] : h1[u - 4];
            const unsigned short hi = f2bf(v);
            ah[u] = (short)hi;
            al[u] = (short)f2bf(v - bf2f(hi));
        }
        const bf16x8 bh = *(const bf16x8*)(bph + kk * 32);
        const bf16x8 bl = *(const bf16x8*)(bpl + kk * 32);
        acc = __builtin_amdgcn_mfma_f32_16x16x32_bf16(ah, bh, acc, 0, 0, 0);
        acc = __builtin_amdgcn_mfma_f32_16x16x32_bf16(al, bh, acc, 0, 0, 0);
        acc = __builtin_amdgcn_mfma_f32_16x16x32_bf16(ah, bl, acc, 0, 0, 0);
    }
    u16x4 o;
#pragma unroll
    for (int r = 0; r < 4; ++r) o[r] = f2bf(acc[r]);
    *(u16x4*)&WhT[(size_t)(nt * 16 + mq) * N + i0 + quad * 4] = o;
}

// ---------------------------------------------------------------------------
// compress v5 (fused rowmax): block = one adj row (256 thr); thread t handles
// int4 indices {t, t+256, ..., t+1792} via 4 pairs of cache-bypassing
// (sc0 sc1 nt) 16 B lane-contiguous loads. Full row coverage (r8's NaN bug
// was partial coverage). Masked per-row max of s2c inline (s2c L1-hot).
// Staleness-safe: adj bytes are identical across replays.
// ---------------------------------------------------------------------------
__global__ __launch_bounds__(256) void compress_kernel(
    const int* __restrict__ adj, const float* __restrict__ s2c,
    const float* __restrict__ s1c,
    unsigned char* __restrict__ maskbits, float* __restrict__ mrowc) {
    __shared__ float red[4];
    const int t = threadIdx.x, wave = t >> 6, lane = t & 63;
    const int row = blockIdx.x;
    const int odd = t & 1;
    const int* __restrict__ arow = adj + (size_t)row * N;
    float mx = -3.0e38f;

#pragma unroll
    for (int pp = 0; pp < 4; ++pp) {
        const int i40 = (2 * pp) * 256 + t;       // int4 index within row
        const int i41 = (2 * pp + 1) * 256 + t;
        i32x4 a0, a1;
        load2_bypass(arow + i40 * 4, arow + i41 * 4, a0, a1);
        const f32x4 s0 = *(const f32x4*)(s2c + i40 * 4);  // cacheable, L1-hot
        const f32x4 s1 = *(const f32x4*)(s2c + i41 * 4);

        const unsigned nib0 =
            (a0[0] > 0 ? 1u : 0u) | (a0[1] > 0 ? 2u : 0u) |
            (a0[2] > 0 ? 4u : 0u) | (a0[3] > 0 ? 8u : 0u);
        const unsigned nib1 =
            (a1[0] > 0 ? 1u : 0u) | (a1[1] > 0 ? 2u : 0u) |
            (a1[2] > 0 ? 4u : 0u) | (a1[3] > 0 ? 8u : 0u);
#pragma unroll
        for (int u = 0; u < 4; ++u) {
            mx = fmaxf(mx, (a0[u] > 0) ? s0[u] : -3.0e38f);
            mx = fmaxf(mx, (a1[u] > 0) ? s1[u] : -3.0e38f);
        }
        const unsigned pn0 = (unsigned)__shfl_xor((int)nib0, 1, 64);
        const unsigned pn1 = (unsigned)__shfl_xor((int)nib1, 1, 64);
        if (!odd) {
            maskbits[(size_t)row * (N / 8) + (i40 >> 1)] = (unsigned char)(nib0 | (pn0 << 4));
            maskbits[(size_t)row * (N / 8) + (i41 >> 1)] = (unsigned char)(nib1 | (pn1 << 4));
        }
    }
#pragma unroll
    for (int off = 32; off; off >>= 1) mx = fmaxf(mx, __shfl_down(mx, off, 64));
    if (lane == 0) red[wave] = mx;
    __syncthreads();
    if (t == 0) {
        const float mm = fmaxf(fmaxf(red[0], red[1]), fmaxf(red[2], red[3]));
        const float xm = s1c[row] + mm;     // exact masked row max (scaled)
        mrowc[row] = fmaxf(xm, ALPHA * xm); // lrelu monotone + scale-invariant
    }
}

// ---------------------------------------------------------------------------
// attn: phase-2 only (validated r5-r9). grid 512 x 512.
// ---------------------------------------------------------------------------
#define AROWS 16
__global__ __launch_bounds__(512, 8) void attn_kernel(
    const unsigned char* __restrict__ maskbits,
    const unsigned short* __restrict__ WhT,
    const float* __restrict__ s1c, const float* __restrict__ s2c,
    const float* __restrict__ mrowc, float* __restrict__ out) {
    __shared__ float s1l[AROWS], ml[AROWS];
    __shared__ __align__(16) float accbuf[8][AROWS][F_OUT];   // 32 KB
    __shared__ float rowsums[8][AROWS];

    const int t = threadIdx.x, wave = t >> 6, lane = t & 63;
    const int i0 = blockIdx.x * AROWS;
    if (t < AROWS) { s1l[t] = s1c[i0 + t]; ml[t] = mrowc[i0 + t]; }
    __syncthreads();

    const int mq = lane & 15, quad = lane >> 4;
    const float s1m = s1l[mq];
    const float mr = ml[mq];
    const int jb0 = wave * 1024;

    const unsigned char* __restrict__ mbp =
        maskbits + (size_t)(i0 + mq) * (N / 8) + (jb0 >> 3) + quad;
    const float* __restrict__ sp = s2c + jb0 + quad * 8;
    const unsigned short* __restrict__ wp = WhT + (size_t)mq * N + jb0 + quad * 8;

    f32x4 acc0 = {0.f, 0.f, 0.f, 0.f}, acc1 = acc0, acc2 = acc0, acc3 = acc0, accS = acc0;
    bf16x8 onesf;
#pragma unroll
    for (int u = 0; u < 8; ++u) onesf[u] = (mq == 0) ? (short)0x3F80 : (short)0;

    for (int c = 0; c < 32; ++c) {
        const unsigned mbyte = mbp[c * 4];
        const f32x4 v0 = *(const f32x4*)(sp + c * 32);
        const f32x4 v1 = *(const f32x4*)(sp + c * 32 + 4);
        const unsigned short* wpc = wp + c * 32;
        const bf16x8 b0 = *(const bf16x8*)(wpc);
        const bf16x8 b1 = *(const bf16x8*)(wpc + 16 * N);
        const bf16x8 b2 = *(const bf16x8*)(wpc + 32 * N);
        const bf16x8 b3 = *(const bf16x8*)(wpc + 48 * N);

        bf16x8 af;
#pragma unroll
        for (int jj = 0; jj < 8; ++jj) {
            const float s2k = (jj < 4) ? v0[jj] : v1[jj - 4];
            const float x = s1m + s2k;                   // scaled score
            const float e = fmaxf(x, ALPHA * x);         // lrelu (scale-invariant)
            const float w = ((mbyte >> jj) & 1u) ? fast_exp2(e - mr) : 0.f;  // <= 1
            af[jj] = (short)(__float_as_uint(w) >> 16);  // truncating bf16 (consistent num/den)
        }
        acc0 = __builtin_amdgcn_mfma_f32_16x16x32_bf16(af, b0, acc0, 0, 0, 0);
        acc1 = __builtin_amdgcn_mfma_f32_16x16x32_bf16(af, b1, acc1, 0, 0, 0);
        acc2 = __builtin_amdgcn_mfma_f32_16x16x32_bf16(af, b2, acc2, 0, 0, 0);
        acc3 = __builtin_amdgcn_mfma_f32_16x16x32_bf16(af, b3, acc3, 0, 0, 0);
        accS = __builtin_amdgcn_mfma_f32_16x16x32_bf16(af, onesf, accS, 0, 0, 0);
    }

#pragma unroll
    for (int r = 0; r < 4; ++r) {
        const int row = quad * 4 + r;
        accbuf[wave][row][0 + mq]  = acc0[r];
        accbuf[wave][row][16 + mq] = acc1[r];
        accbuf[wave][row][32 + mq] = acc2[r];
        accbuf[wave][row][48 + mq] = acc3[r];
        if (mq == 0) rowsums[wave][row] = accS[r];
    }
    __syncthreads();

    {
        const int row = t >> 5, f0 = (t & 31) * 2;
        float o0 = 0.f, o1 = 0.f, rs = 0.f;
#pragma unroll
        for (int w = 0; w < 8; ++w) {
            o0 += accbuf[w][row][f0];
            o1 += accbuf[w][row][f0 + 1];
            rs += rowsums[w][row];
        }
        const float inv = (rs > 0.f) ? 1.f / rs : 0.f;
        float2 st = {o0 * inv, o1 * inv};
        *(float2*)&out[(size_t)(i0 + row) * F_OUT + f0] = st;
    }
}

extern "C" void kernel_launch(void* const* d_in, const int* in_sizes, int n_in,
                              void* d_out, int out_size, void* d_ws, size_t ws_size,
                              hipStream_t stream) {
    const float* h   = (const float*)d_in[0];
    const int*   adj = (const int*)d_in[1];
    const float* W   = (const float*)d_in[2];
    const float* a   = (const float*)d_in[3];
    float* out = (float*)d_out;

    // workspace layout (~9.6 MB)
    char* ws = (char*)d_ws;
    unsigned char* maskbits = (unsigned char*)ws;                        // 8 MB
    unsigned short* WhT = (unsigned short*)(ws + (size_t)N * (N / 8));   // 1 MB
    float* s1c  = (float*)((char*)WhT + (size_t)F_OUT * N * 2);          // 32 KB
    float* s2c  = s1c + N;                                               // 32 KB
    float* mrowc = s2c + N;                                              // 32 KB
    float* Wa1 = mrowc + N;
    float* Wa2 = Wa1 + F_IN;
    unsigned short* WbTh = (unsigned short*)(Wa2 + F_IN);                // 32 KB
    unsigned short* WbTl = WbTh + F_OUT * F_IN;                          // 32 KB

    prep_kernel<<<1, 256, 0, stream>>>(W, a, Wa1, Wa2, WbTh, WbTl);
    score_kernel<<<N / 16, 256, 0, stream>>>(h, Wa1, Wa2, s1c, s2c);
    whT_kernel<<<N / 16, 256, 0, stream>>>(h, WbTh, WbTl, WhT);
    compress_kernel<<<N, 256, 0, stream>>>(adj, s2c, s1c, maskbits, mrowc);
    attn_kernel<<<N / AROWS, 512, 0, stream>>>(maskbits, WhT, s1c, s2c, mrowc, out);
}